// Round 1
// baseline (1801.098 us; speedup 1.0000x reference)
//
#include <hip/hip_runtime.h>

#define N_NODES 10000
#define N_EDGES 160000
#define NUM_FEAT 14
#define EDGE_DIM 4
#define DIM 64
#define HID 128
#define LAYERS 28

#define NEG_INF (-__builtin_inff())

// ---------------- CSR build ----------------

__global__ __launch_bounds__(256) void k_zero(int* __restrict__ p, int n) {
  int i = blockIdx.x * 256 + threadIdx.x;
  if (i < n) p[i] = 0;
}

__global__ __launch_bounds__(256) void k_hist(const int* __restrict__ dst, int* __restrict__ cur) {
  int e = blockIdx.x * 256 + threadIdx.x;
  if (e < N_EDGES) atomicAdd(&cur[dst[e]], 1);
}

// single block, 256 threads: exclusive scan of degrees -> off[0..N], cur[i]=off[i]
__global__ __launch_bounds__(256) void k_scan(int* __restrict__ cur, int* __restrict__ off) {
  __shared__ int part[256];
  int t = threadIdx.x;
  const int CH = 40;  // 256*40 = 10240 >= N_NODES
  int base = t * CH;
  int s = 0;
  for (int i = 0; i < CH; i++) {
    int idx = base + i;
    if (idx < N_NODES) s += cur[idx];
  }
  part[t] = s;
  __syncthreads();
  for (int ofs = 1; ofs < 256; ofs <<= 1) {
    int tmp = (t >= ofs) ? part[t - ofs] : 0;
    __syncthreads();
    part[t] += tmp;
    __syncthreads();
  }
  int run = part[t] - s;  // exclusive prefix of this chunk
  for (int i = 0; i < CH; i++) {
    int idx = base + i;
    if (idx < N_NODES) {
      int d = cur[idx];
      off[idx] = run;
      cur[idx] = run;
      run += d;
    }
  }
  if (t == 255) off[N_NODES] = part[255];
}

__global__ __launch_bounds__(256) void k_scatter(const int* __restrict__ dst, int* __restrict__ cur,
                                                 int* __restrict__ eids) {
  int e = blockIdx.x * 256 + threadIdx.x;
  if (e < N_EDGES) {
    int p = atomicAdd(&cur[dst[e]], 1);
    eids[p] = e;
  }
}

// deterministic order: sort each node's edge list by edge id (thread per node)
__global__ __launch_bounds__(256) void k_sort(const int* __restrict__ off, int* __restrict__ eids) {
  int n = blockIdx.x * 256 + threadIdx.x;
  if (n >= N_NODES) return;
  int a = off[n], b = off[n + 1];
  for (int i = a + 1; i < b; i++) {
    int v = eids[i];
    int j = i - 1;
    while (j >= a && eids[j] > v) { eids[j + 1] = eids[j]; j--; }
    eids[j + 1] = v;
  }
}

// ---------------- node encoder ----------------

__global__ __launch_bounds__(256) void k_enc(const float* __restrict__ x, const float* __restrict__ Wn,
                                             const float* __restrict__ bn, float* __restrict__ hc,
                                             float* __restrict__ u) {
  int gid = blockIdx.x * 256 + threadIdx.x;
  if (gid >= N_NODES * DIM) return;
  int n = gid >> 6, j = gid & 63;
  float acc = bn[j];
#pragma unroll
  for (int k = 0; k < NUM_FEAT; k++) acc += x[n * NUM_FEAT + k] * Wn[k * DIM + j];
  hc[gid] = acc;
  u[gid] = acc;
}

// ---------------- edge aggregation (softmax attention), wave per node ----------------
// ea computed on the fly: ea[e][f] = b_edge[f] + sum_k edge_attr[e][k]*W_edge[k][f]
// per-lane (per-feature) online softmax; CSR-sorted order => deterministic.

__global__ __launch_bounds__(256) void k_edge_agg(
    const float* __restrict__ u, const float* __restrict__ eattr,
    const float* __restrict__ W_edge, const float* __restrict__ b_edge,
    const int* __restrict__ src, const int* __restrict__ off, const int* __restrict__ eids,
    const float* __restrict__ tptr, int layer, float* __restrict__ htmp) {
  int node = ((int)blockIdx.x << 2) + (threadIdx.x >> 6);
  int lane = threadIdx.x & 63;
  if (node >= N_NODES) return;
  float tv = tptr[layer];
  float w0 = W_edge[lane], w1 = W_edge[64 + lane], w2 = W_edge[128 + lane], w3 = W_edge[192 + lane];
  float be = b_edge[lane];
  int a = off[node], bEnd = off[node + 1];
  float m = NEG_INF, sum = 0.f, acc = 0.f;
  for (int i = a; i < bEnd; i++) {
    int e = eids[i];
    int sn = src[e];
    float4 ev = ((const float4*)eattr)[e];
    float msg = u[(sn << 6) + lane] + be + ev.x * w0 + ev.y * w1 + ev.z * w2 + ev.w * w3;
    msg = fmaxf(msg, 0.f) + 1e-7f;
    float lg = msg * tv;
    float mn = fmaxf(m, lg);
    float sc = __expf(m - mn);   // exp(-inf)=0 on first edge
    float wv = __expf(lg - mn);
    sum = sum * sc + wv;
    acc = acc * sc + wv * msg;
    m = mn;
  }
  htmp[(node << 6) + lane] = acc / (sum + 1e-16f) + u[(node << 6) + lane];
}

// ---------------- fused MLP + residual + next-layer pre-LN ----------------
// out = relu(LN(h@W1+b1, g1, be1)) @ W2 + b2 ; hc = (addRes? hc : 0) + out ;
// if writeU: u = relu(LN(hc, lng, lnb))
// block 256 threads, tile of 32 nodes; W1/W2 staged in LDS (once per block).

#define NT_TILES ((N_NODES + 31) / 32)

__global__ __launch_bounds__(256) void k_mlp(
    const float* __restrict__ hin, float* __restrict__ hc, float* __restrict__ uout,
    const float* __restrict__ W1, const float* __restrict__ b1,
    const float* __restrict__ g1, const float* __restrict__ be1,
    const float* __restrict__ W2, const float* __restrict__ b2,
    const float* __restrict__ lng, const float* __restrict__ lnb,
    int addRes, int writeU) {
  __shared__ float sW1[DIM * HID];       // 32 KB, [k][j]
  __shared__ float sW2[HID * DIM];       // 32 KB, [k][i]
  __shared__ float sHt[DIM * 33];        // transposed h tile, padded
  __shared__ float sZ[32 * 130];         // relu(LN(...)) tile, padded
  __shared__ float sP[512];              // reduction partials
  __shared__ float sMu[32], sRs[32];

  int tid = threadIdx.x;
  for (int i = tid; i < 2048; i += 256) ((float4*)sW1)[i] = ((const float4*)W1)[i];
  for (int i = tid; i < 2048; i += 256) ((float4*)sW2)[i] = ((const float4*)W2)[i];

  int n = tid & 31;
  int jg = tid >> 5;   // 0..7
  int j0 = jg * 16;    // GEMM1: 16 hidden per thread
  int i0 = jg * 8;     // GEMM2: 8 outputs per thread

  for (int tile = blockIdx.x; tile < NT_TILES; tile += gridDim.x) {
    int t0 = tile * 32;
    __syncthreads();  // covers weight load (1st iter) + LDS reuse (later iters)

    for (int i = tid; i < 2048; i += 256) {
      int nl = i >> 6, k = i & 63;
      int ng = t0 + nl;
      sHt[k * 33 + nl] = (ng < N_NODES) ? hin[ng * 64 + k] : 0.f;
    }
    __syncthreads();

    // GEMM1: acc[q] = b1[j0+q] + sum_k h[n][k] * W1[k][j0+q]
    float acc[16];
#pragma unroll
    for (int q = 0; q < 16; q++) acc[q] = b1[j0 + q];
    for (int k = 0; k < 64; k++) {
      float av = sHt[k * 33 + n];
      const float4* w4 = (const float4*)(&sW1[k * 128 + j0]);
      float wv[16];
      ((float4*)wv)[0] = w4[0];
      ((float4*)wv)[1] = w4[1];
      ((float4*)wv)[2] = w4[2];
      ((float4*)wv)[3] = w4[3];
#pragma unroll
      for (int q = 0; q < 16; q++) acc[q] += av * wv[q];
    }

    // LN over HID=128
    float ps = 0.f, pq = 0.f;
#pragma unroll
    for (int q = 0; q < 16; q++) { ps += acc[q]; pq += acc[q] * acc[q]; }
    sP[jg * 32 + n] = ps;
    sP[256 + jg * 32 + n] = pq;
    __syncthreads();
    if (tid < 32) {
      float s = 0.f, q2 = 0.f;
      for (int g = 0; g < 8; g++) { s += sP[g * 32 + tid]; q2 += sP[256 + g * 32 + tid]; }
      float mu = s * (1.f / 128.f);
      float var = q2 * (1.f / 128.f) - mu * mu;
      sMu[tid] = mu;
      sRs[tid] = rsqrtf(var + 1e-5f);
    }
    __syncthreads();
    float mu = sMu[n], rs = sRs[n];
#pragma unroll
    for (int q = 0; q < 16; q += 2) {
      float z0 = fmaxf((acc[q] - mu) * rs * g1[j0 + q] + be1[j0 + q], 0.f);
      float z1 = fmaxf((acc[q + 1] - mu) * rs * g1[j0 + q + 1] + be1[j0 + q + 1], 0.f);
      float2 z2; z2.x = z0; z2.y = z1;
      *((float2*)&sZ[n * 130 + j0 + q]) = z2;
    }
    __syncthreads();

    // GEMM2: o[q] = b2[i0+q] + sum_k z[n][k] * W2[k][i0+q]
    float o[8];
#pragma unroll
    for (int q = 0; q < 8; q++) o[q] = b2[i0 + q];
    for (int k = 0; k < 128; k++) {
      float av = sZ[n * 130 + k];
      const float4* w4 = (const float4*)(&sW2[k * 64 + i0]);
      float wv[8];
      ((float4*)wv)[0] = w4[0];
      ((float4*)wv)[1] = w4[1];
#pragma unroll
      for (int q = 0; q < 8; q++) o[q] += av * wv[q];
    }

    int ng = t0 + n;
    float hcn[8];
    if (ng < N_NODES) {
      float r[8];
      if (addRes) {
        ((float4*)r)[0] = ((const float4*)&hc[ng * 64 + i0])[0];
        ((float4*)r)[1] = ((const float4*)&hc[ng * 64 + i0])[1];
      } else {
#pragma unroll
        for (int q = 0; q < 8; q++) r[q] = 0.f;
      }
#pragma unroll
      for (int q = 0; q < 8; q++) hcn[q] = o[q] + r[q];
      ((float4*)&hc[ng * 64 + i0])[0] = ((float4*)hcn)[0];
      ((float4*)&hc[ng * 64 + i0])[1] = ((float4*)hcn)[1];
    } else {
#pragma unroll
      for (int q = 0; q < 8; q++) hcn[q] = 0.f;
    }

    if (writeU) {
      float ps2 = 0.f, pq2 = 0.f;
#pragma unroll
      for (int q = 0; q < 8; q++) { ps2 += hcn[q]; pq2 += hcn[q] * hcn[q]; }
      sP[jg * 32 + n] = ps2;
      sP[256 + jg * 32 + n] = pq2;
      __syncthreads();
      if (tid < 32) {
        float s = 0.f, q2 = 0.f;
        for (int g = 0; g < 8; g++) { s += sP[g * 32 + tid]; q2 += sP[256 + g * 32 + tid]; }
        float mu2 = s * (1.f / 64.f);
        float var2 = q2 * (1.f / 64.f) - mu2 * mu2;
        sMu[tid] = mu2;
        sRs[tid] = rsqrtf(var2 + 1e-5f);
      }
      __syncthreads();
      if (ng < N_NODES) {
        float mu2 = sMu[n], rs2 = sRs[n];
        float uo[8];
#pragma unroll
        for (int q = 0; q < 8; q++)
          uo[q] = fmaxf((hcn[q] - mu2) * rs2 * lng[i0 + q] + lnb[i0 + q], 0.f);
        ((float4*)&uout[ng * 64 + i0])[0] = ((float4*)uo)[0];
        ((float4*)&uout[ng * 64 + i0])[1] = ((float4*)uo)[1];
      }
    }
  }
}

// ---------------- final: out = relu(LN(hc, g0, b0)) @ W_out + b_out ----------------

__global__ __launch_bounds__(256) void k_final(const float* __restrict__ hc, const float* __restrict__ g,
                                               const float* __restrict__ bptr, const float* __restrict__ Wout,
                                               const float* __restrict__ bout, float* __restrict__ out) {
  __shared__ float sW[DIM * DIM];
  int tid = threadIdx.x;
  for (int i = tid; i < 1024; i += 256) ((float4*)sW)[i] = ((const float4*)Wout)[i];
  __syncthreads();
  int lane = tid & 63, w = tid >> 6;
  int n = blockIdx.x * 4 + w;
  if (n >= N_NODES) return;
  float v = hc[n * 64 + lane];
  float s = v, q = v * v;
#pragma unroll
  for (int o = 32; o; o >>= 1) { s += __shfl_xor(s, o); q += __shfl_xor(q, o); }
  float mu = s * (1.f / 64.f);
  float var = q * (1.f / 64.f) - mu * mu;
  float rs = rsqrtf(var + 1e-5f);
  float z = fmaxf((v - mu) * rs * g[lane] + bptr[lane], 0.f);
  float acc = bout[lane];
  for (int k = 0; k < 64; k++) {
    float zk = __shfl(z, k);
    acc += zk * sW[k * 64 + lane];
  }
  out[n * 64 + lane] = acc;
}

// ---------------- host ----------------

extern "C" void kernel_launch(void* const* d_in, const int* in_sizes, int n_in,
                              void* d_out, int out_size, void* d_ws, size_t ws_size,
                              hipStream_t stream) {
  const float* x        = (const float*)d_in[0];
  const float* eattr    = (const float*)d_in[1];
  const int*   src      = (const int*)d_in[2];
  const int*   dst      = (const int*)d_in[3];
  const float* W_node   = (const float*)d_in[4];
  const float* b_node   = (const float*)d_in[5];
  const float* W_edge   = (const float*)d_in[6];
  const float* b_edge   = (const float*)d_in[7];
  const float* t        = (const float*)d_in[8];
  const float* W1       = (const float*)d_in[9];
  const float* b1       = (const float*)d_in[10];
  const float* g1       = (const float*)d_in[11];
  const float* be1      = (const float*)d_in[12];
  const float* W2       = (const float*)d_in[13];
  const float* b2       = (const float*)d_in[14];
  const float* ln_g     = (const float*)d_in[15];
  const float* ln_b     = (const float*)d_in[16];
  const float* W_out    = (const float*)d_in[17];
  const float* b_out    = (const float*)d_in[18];
  float* out = (float*)d_out;

  char* w = (char*)d_ws;
  float* u    = (float*)w;  w += (size_t)N_NODES * 64 * 4;
  float* hcb  = (float*)w;  w += (size_t)N_NODES * 64 * 4;
  float* htmp = (float*)w;  w += (size_t)N_NODES * 64 * 4;
  int* off    = (int*)w;    w += (size_t)(N_NODES + 1) * 4;
  int* cur    = (int*)w;    w += (size_t)N_NODES * 4;
  int* eids   = (int*)w;    w += (size_t)N_EDGES * 4;

  // CSR build (deterministic: int atomics + per-node sort by edge id)
  k_zero<<<(N_NODES + 255) / 256, 256, 0, stream>>>(cur, N_NODES);
  k_hist<<<(N_EDGES + 255) / 256, 256, 0, stream>>>(dst, cur);
  k_scan<<<1, 256, 0, stream>>>(cur, off);
  k_scatter<<<(N_EDGES + 255) / 256, 256, 0, stream>>>(dst, cur, eids);
  k_sort<<<(N_NODES + 255) / 256, 256, 0, stream>>>(off, eids);

  // node encoder -> hc and u (layer-0 input)
  k_enc<<<(N_NODES * 64 + 255) / 256, 256, 0, stream>>>(x, W_node, b_node, hcb, u);

  for (int l = 0; l < LAYERS; l++) {
    k_edge_agg<<<(N_NODES + 3) / 4, 256, 0, stream>>>(u, eattr, W_edge, b_edge, src, off, eids,
                                                      t, l, htmp);
    int nxt = (l + 1 < LAYERS) ? (l + 1) : 0;  // unused when writeU=0
    k_mlp<<<256, 256, 0, stream>>>(htmp, hcb, u,
                                   W1 + (size_t)l * DIM * HID, b1 + (size_t)l * HID,
                                   g1 + (size_t)l * HID, be1 + (size_t)l * HID,
                                   W2 + (size_t)l * HID * DIM, b2 + (size_t)l * DIM,
                                   ln_g + (size_t)nxt * DIM, ln_b + (size_t)nxt * DIM,
                                   (l > 0) ? 1 : 0, (l < LAYERS - 1) ? 1 : 0);
  }

  k_final<<<(N_NODES + 3) / 4, 256, 0, stream>>>(hcb, ln_g, ln_b, W_out, b_out, out);
}

// Round 2
// 1205.626 us; speedup vs baseline: 1.4939x; 1.4939x over previous
//
#include <hip/hip_runtime.h>

#define N_NODES 10000
#define N_EDGES 160000
#define NUM_FEAT 14
#define EDGE_DIM 4
#define DIM 64
#define HID 128
#define LAYERS 28

#define NEG_INF (-__builtin_inff())

// ---------------- CSR build ----------------

__global__ __launch_bounds__(256) void k_zero(int* __restrict__ p, int n) {
  int i = blockIdx.x * 256 + threadIdx.x;
  if (i < n) p[i] = 0;
}

__global__ __launch_bounds__(256) void k_hist(const int* __restrict__ dst, int* __restrict__ cur) {
  int e = blockIdx.x * 256 + threadIdx.x;
  if (e < N_EDGES) atomicAdd(&cur[dst[e]], 1);
}

// single block, 256 threads: exclusive scan of degrees -> off[0..N], cur[i]=off[i]
__global__ __launch_bounds__(256) void k_scan(int* __restrict__ cur, int* __restrict__ off) {
  __shared__ int part[256];
  int t = threadIdx.x;
  const int CH = 40;  // 256*40 = 10240 >= N_NODES
  int base = t * CH;
  int s = 0;
  for (int i = 0; i < CH; i++) {
    int idx = base + i;
    if (idx < N_NODES) s += cur[idx];
  }
  part[t] = s;
  __syncthreads();
  for (int ofs = 1; ofs < 256; ofs <<= 1) {
    int tmp = (t >= ofs) ? part[t - ofs] : 0;
    __syncthreads();
    part[t] += tmp;
    __syncthreads();
  }
  int run = part[t] - s;  // exclusive prefix of this chunk
  for (int i = 0; i < CH; i++) {
    int idx = base + i;
    if (idx < N_NODES) {
      int d = cur[idx];
      off[idx] = run;
      cur[idx] = run;
      run += d;
    }
  }
  if (t == 255) off[N_NODES] = part[255];
}

__global__ __launch_bounds__(256) void k_scatter(const int* __restrict__ dst, int* __restrict__ cur,
                                                 int* __restrict__ eids) {
  int e = blockIdx.x * 256 + threadIdx.x;
  if (e < N_EDGES) {
    int p = atomicAdd(&cur[dst[e]], 1);
    eids[p] = e;
  }
}

// Deterministic order without serial sort: wave-per-node bitonic sort of edge ids
// (64 lanes, shfl_xor), then gather src/eattr into CSR-slot order once.
__global__ __launch_bounds__(256) void k_sortgather(
    const int* __restrict__ off, const int* __restrict__ eids,
    const int* __restrict__ src, const float4* __restrict__ eattr,
    int* __restrict__ src_s, float4* __restrict__ eattr_s) {
  int node = blockIdx.x * 4 + (threadIdx.x >> 6);
  int lane = threadIdx.x & 63;
  if (node >= N_NODES) return;
  int a = off[node];
  int d = off[node + 1] - a;
  if (d <= 64) {
    int key = (lane < d) ? eids[a + lane] : 0x7fffffff;
#pragma unroll
    for (int k = 2; k <= 64; k <<= 1) {
      for (int j = k >> 1; j > 0; j >>= 1) {
        int p = __shfl_xor(key, j);
        bool dirUp = ((lane & k) == 0);
        bool isLower = ((lane & j) == 0);
        key = ((isLower == dirUp) ? min(key, p) : max(key, p));
      }
    }
    if (lane < d) {
      int e = key;
      src_s[a + lane] = src[e];
      eattr_s[a + lane] = eattr[e];
    }
  } else {
    // rare fallback: counting rank (edge ids unique -> exact, deterministic)
    for (int i = lane; i < d; i += 64) {
      int e = eids[a + i];
      int r = 0;
      for (int j = 0; j < d; j++) r += (eids[a + j] < e) ? 1 : 0;
      src_s[a + r] = src[e];
      eattr_s[a + r] = eattr[e];
    }
  }
}

// ---------------- node encoder ----------------

__global__ __launch_bounds__(256) void k_enc(const float* __restrict__ x, const float* __restrict__ Wn,
                                             const float* __restrict__ bn, float* __restrict__ hc,
                                             float* __restrict__ u) {
  int gid = blockIdx.x * 256 + threadIdx.x;
  if (gid >= N_NODES * DIM) return;
  int n = gid >> 6, j = gid & 63;
  float acc = bn[j];
#pragma unroll
  for (int k = 0; k < NUM_FEAT; k++) acc += x[n * NUM_FEAT + k] * Wn[k * DIM + j];
  hc[gid] = acc;
  u[gid] = acc;
}

// ---------------- edge aggregation (softmax attention), wave per node ----------------
// Pre-gathered CSR-sorted src/eattr; batch-8 independent u-row gathers to break
// the per-edge dependent-load chain. Per-lane (per-feature) online softmax;
// fixed slot order => deterministic.

__global__ __launch_bounds__(256) void k_edge_agg(
    const float* __restrict__ u, const float4* __restrict__ eattr_s,
    const int* __restrict__ src_s,
    const float* __restrict__ W_edge, const float* __restrict__ b_edge,
    const int* __restrict__ off,
    const float* __restrict__ tptr, int layer, float* __restrict__ htmp) {
  int node = (blockIdx.x << 2) + (threadIdx.x >> 6);
  int lane = threadIdx.x & 63;
  if (node >= N_NODES) return;
  float tv = tptr[layer];
  float w0 = W_edge[lane], w1 = W_edge[64 + lane], w2 = W_edge[128 + lane], w3 = W_edge[192 + lane];
  float be = b_edge[lane];
  int a = off[node], d = off[node + 1] - a;
  float un = u[(node << 6) + lane];
  float m = NEG_INF, sum = 0.f, acc = 0.f;
  for (int i = 0; i < d; i += 8) {
    int b = min(8, d - i);
    float msg[8];
#pragma unroll
    for (int j = 0; j < 8; j++) {
      if (j < b) {
        int sn = src_s[a + i + j];
        float4 ev = eattr_s[a + i + j];
        float uv = u[(sn << 6) + lane];
        msg[j] = fmaxf(uv + be + ev.x * w0 + ev.y * w1 + ev.z * w2 + ev.w * w3, 0.f) + 1e-7f;
      }
    }
#pragma unroll
    for (int j = 0; j < 8; j++) {
      if (j < b) {
        float lg = msg[j] * tv;
        float mn = fmaxf(m, lg);
        float sc = __expf(m - mn);  // exp(-inf)=0 on first edge
        float wv = __expf(lg - mn);
        sum = sum * sc + wv;
        acc = acc * sc + wv * msg[j];
        m = mn;
      }
    }
  }
  htmp[(node << 6) + lane] = acc / (sum + 1e-16f) + un;
}

// ---------------- fused MLP + residual + next-layer pre-LN ----------------
// Tile = 32 nodes per block, 256 threads. Register blocking: each thread owns
// a 4-node x 4-col block in both GEMMs (ds_read_b128 amortized over 4 nodes).
// W1 then W2 time-share one 32KB LDS buffer; h-tile (transposed) then z-tile
// (transposed) time-share an 18KB buffer. ~58.5KB LDS -> 2 blocks/CU.

#define TILE 32
#define NT_TILES ((N_NODES + TILE - 1) / TILE)

__global__ __launch_bounds__(256) void k_mlp(
    const float* __restrict__ hin, float* __restrict__ hc, float* __restrict__ uout,
    const float* __restrict__ W1, const float* __restrict__ b1,
    const float* __restrict__ g1, const float* __restrict__ be1,
    const float* __restrict__ W2, const float* __restrict__ b2,
    const float* __restrict__ lng, const float* __restrict__ lnb,
    int addRes, int writeU) {
  __shared__ float sW[64 * 128];   // 32KB: W1 (64x128), then W2 (128x64)
  __shared__ float sT[128 * 36];   // 18KB: hT[64][36] (k-major), then zT[128][36] (j-major)
  __shared__ float sPs[32 * 32];
  __shared__ float sPq[32 * 32];
  __shared__ float sMu[TILE], sRs[TILE];

  int tid = threadIdx.x;
  int t0 = blockIdx.x * TILE;

  // stage W1 + transposed h-tile
  for (int i = tid; i < 2048; i += 256) ((float4*)sW)[i] = ((const float4*)W1)[i];
  for (int i = tid; i < 512; i += 256) {
    int nl = i >> 4, kq = i & 15;
    int n = t0 + nl;
    float4 hv = (n < N_NODES) ? ((const float4*)hin)[n * 16 + kq]
                              : make_float4(0.f, 0.f, 0.f, 0.f);
    sT[(4 * kq + 0) * 36 + nl] = hv.x;
    sT[(4 * kq + 1) * 36 + nl] = hv.y;
    sT[(4 * kq + 2) * 36 + nl] = hv.z;
    sT[(4 * kq + 3) * 36 + nl] = hv.w;
  }
  __syncthreads();

  int ng = tid & 7;       // node group: nodes n0..n0+3
  int n0 = ng * 4;
  int jg = tid >> 3;      // 0..31
  int j0 = jg * 4;        // GEMM1 cols
  int o0 = jg * 2;        // GEMM2 cols

  // ---- GEMM1: acc[4 nodes][4 hid] ----
  float4 b1v = *((const float4*)&b1[j0]);
  float acc[4][4];
#pragma unroll
  for (int q = 0; q < 4; q++) {
    acc[q][0] = b1v.x; acc[q][1] = b1v.y; acc[q][2] = b1v.z; acc[q][3] = b1v.w;
  }
  for (int k = 0; k < 64; k++) {
    float4 hv = *((float4*)&sT[k * 36 + n0]);
    float4 wv = *((float4*)&sW[k * 128 + j0]);
    float h_[4] = {hv.x, hv.y, hv.z, hv.w};
    float w_[4] = {wv.x, wv.y, wv.z, wv.w};
#pragma unroll
    for (int q = 0; q < 4; q++)
#pragma unroll
      for (int p = 0; p < 4; p++) acc[q][p] += h_[q] * w_[p];
  }

  // ---- LN1 partials ----
#pragma unroll
  for (int q = 0; q < 4; q++) {
    float ps = acc[q][0] + acc[q][1] + acc[q][2] + acc[q][3];
    float pq = acc[q][0] * acc[q][0] + acc[q][1] * acc[q][1] +
               acc[q][2] * acc[q][2] + acc[q][3] * acc[q][3];
    sPs[jg * 32 + n0 + q] = ps;
    sPq[jg * 32 + n0 + q] = pq;
  }
  __syncthreads();  // B1: GEMM1 + partials done

  // load W2 while stats reduce (sW no longer read)
  for (int i = tid; i < 2048; i += 256) ((float4*)sW)[i] = ((const float4*)W2)[i];
  if (tid < TILE) {
    float s = 0.f, qq = 0.f;
    for (int g = 0; g < 32; g++) { s += sPs[g * 32 + tid]; qq += sPq[g * 32 + tid]; }
    float mu = s * (1.f / 128.f);
    float var = qq * (1.f / 128.f) - mu * mu;
    sMu[tid] = mu;
    sRs[tid] = rsqrtf(var + 1e-5f);
  }
  __syncthreads();  // B2: stats + W2 ready

  // ---- LN1 apply + relu -> zT[j][n] ----
  float4 gv = *((const float4*)&g1[j0]);
  float4 bev = *((const float4*)&be1[j0]);
  float g_[4] = {gv.x, gv.y, gv.z, gv.w};
  float be_[4] = {bev.x, bev.y, bev.z, bev.w};
  float mu_[4], rs_[4];
#pragma unroll
  for (int q = 0; q < 4; q++) { mu_[q] = sMu[n0 + q]; rs_[q] = sRs[n0 + q]; }
#pragma unroll
  for (int p = 0; p < 4; p++) {
    float4 zv;
    zv.x = fmaxf((acc[0][p] - mu_[0]) * rs_[0] * g_[p] + be_[p], 0.f);
    zv.y = fmaxf((acc[1][p] - mu_[1]) * rs_[1] * g_[p] + be_[p], 0.f);
    zv.z = fmaxf((acc[2][p] - mu_[2]) * rs_[2] * g_[p] + be_[p], 0.f);
    zv.w = fmaxf((acc[3][p] - mu_[3]) * rs_[3] * g_[p] + be_[p], 0.f);
    *((float4*)&sT[(j0 + p) * 36 + n0]) = zv;
  }
  __syncthreads();  // B3: zT ready

  // ---- GEMM2: o[4 nodes][2 out] ----
  float2 b2v = *((const float2*)&b2[o0]);
  float o_[4][2];
#pragma unroll
  for (int q = 0; q < 4; q++) { o_[q][0] = b2v.x; o_[q][1] = b2v.y; }
  for (int k = 0; k < 128; k++) {
    float4 zv = *((float4*)&sT[k * 36 + n0]);
    float2 wv = *((float2*)&sW[k * 64 + o0]);
    float z_[4] = {zv.x, zv.y, zv.z, zv.w};
#pragma unroll
    for (int q = 0; q < 4; q++) {
      o_[q][0] += z_[q] * wv.x;
      o_[q][1] += z_[q] * wv.y;
    }
  }

  // ---- residual + hc write ----
  float hcn[4][2];
#pragma unroll
  for (int q = 0; q < 4; q++) {
    int n = t0 + n0 + q;
    if (n < N_NODES) {
      float2 r = addRes ? *((const float2*)&hc[n * 64 + o0]) : make_float2(0.f, 0.f);
      hcn[q][0] = o_[q][0] + r.x;
      hcn[q][1] = o_[q][1] + r.y;
      float2 wv2 = make_float2(hcn[q][0], hcn[q][1]);
      *((float2*)&hc[n * 64 + o0]) = wv2;
    } else {
      hcn[q][0] = 0.f; hcn[q][1] = 0.f;
    }
  }

  // ---- next-layer pre-LN: u = relu(LN(hc)) ----
  if (writeU) {
#pragma unroll
    for (int q = 0; q < 4; q++) {
      sPs[jg * 32 + n0 + q] = hcn[q][0] + hcn[q][1];
      sPq[jg * 32 + n0 + q] = hcn[q][0] * hcn[q][0] + hcn[q][1] * hcn[q][1];
    }
    __syncthreads();  // B4
    if (tid < TILE) {
      float s = 0.f, qq = 0.f;
      for (int g = 0; g < 32; g++) { s += sPs[g * 32 + tid]; qq += sPq[g * 32 + tid]; }
      float mu = s * (1.f / 64.f);
      float var = qq * (1.f / 64.f) - mu * mu;
      sMu[tid] = mu;
      sRs[tid] = rsqrtf(var + 1e-5f);
    }
    __syncthreads();  // B5
    float2 lgv = *((const float2*)&lng[o0]);
    float2 lbv = *((const float2*)&lnb[o0]);
#pragma unroll
    for (int q = 0; q < 4; q++) {
      int n = t0 + n0 + q;
      if (n < N_NODES) {
        float mu = sMu[n0 + q], rs = sRs[n0 + q];
        float2 uv;
        uv.x = fmaxf((hcn[q][0] - mu) * rs * lgv.x + lbv.x, 0.f);
        uv.y = fmaxf((hcn[q][1] - mu) * rs * lgv.y + lbv.y, 0.f);
        *((float2*)&uout[n * 64 + o0]) = uv;
      }
    }
  }
}

// ---------------- final: out = relu(LN(hc, g0, b0)) @ W_out + b_out ----------------

__global__ __launch_bounds__(256) void k_final(const float* __restrict__ hc, const float* __restrict__ g,
                                               const float* __restrict__ bptr, const float* __restrict__ Wout,
                                               const float* __restrict__ bout, float* __restrict__ out) {
  __shared__ float sW[DIM * DIM];
  int tid = threadIdx.x;
  for (int i = tid; i < 1024; i += 256) ((float4*)sW)[i] = ((const float4*)Wout)[i];
  __syncthreads();
  int lane = tid & 63, w = tid >> 6;
  int n = blockIdx.x * 4 + w;
  if (n >= N_NODES) return;
  float v = hc[n * 64 + lane];
  float s = v, q = v * v;
#pragma unroll
  for (int o = 32; o; o >>= 1) { s += __shfl_xor(s, o); q += __shfl_xor(q, o); }
  float mu = s * (1.f / 64.f);
  float var = q * (1.f / 64.f) - mu * mu;
  float rs = rsqrtf(var + 1e-5f);
  float z = fmaxf((v - mu) * rs * g[lane] + bptr[lane], 0.f);
  float acc = bout[lane];
  for (int k = 0; k < 64; k++) {
    float zk = __shfl(z, k);
    acc += zk * sW[k * 64 + lane];
  }
  out[n * 64 + lane] = acc;
}

// ---------------- host ----------------

extern "C" void kernel_launch(void* const* d_in, const int* in_sizes, int n_in,
                              void* d_out, int out_size, void* d_ws, size_t ws_size,
                              hipStream_t stream) {
  const float* x        = (const float*)d_in[0];
  const float* eattr    = (const float*)d_in[1];
  const int*   src      = (const int*)d_in[2];
  const int*   dst      = (const int*)d_in[3];
  const float* W_node   = (const float*)d_in[4];
  const float* b_node   = (const float*)d_in[5];
  const float* W_edge   = (const float*)d_in[6];
  const float* b_edge   = (const float*)d_in[7];
  const float* t        = (const float*)d_in[8];
  const float* W1       = (const float*)d_in[9];
  const float* b1       = (const float*)d_in[10];
  const float* g1       = (const float*)d_in[11];
  const float* be1      = (const float*)d_in[12];
  const float* W2       = (const float*)d_in[13];
  const float* b2       = (const float*)d_in[14];
  const float* ln_g     = (const float*)d_in[15];
  const float* ln_b     = (const float*)d_in[16];
  const float* W_out    = (const float*)d_in[17];
  const float* b_out    = (const float*)d_in[18];
  float* out = (float*)d_out;

  char* w = (char*)d_ws;
  float* u       = (float*)w;  w += (size_t)N_NODES * 64 * 4;
  float* hcb     = (float*)w;  w += (size_t)N_NODES * 64 * 4;
  float* htmp    = (float*)w;  w += (size_t)N_NODES * 64 * 4;
  int* off       = (int*)w;    w += (size_t)(N_NODES + 1) * 4;
  int* cur       = (int*)w;    w += (size_t)N_NODES * 4;
  int* eids      = (int*)w;    w += (size_t)N_EDGES * 4;
  int* src_s     = (int*)w;    w += (size_t)N_EDGES * 4;
  float4* eattr_s = (float4*)w; w += (size_t)N_EDGES * 16;

  // CSR build (deterministic: values from atomics are order-independent;
  // per-node bitonic sort by edge id fixes slot order)
  k_zero<<<(N_NODES + 255) / 256, 256, 0, stream>>>(cur, N_NODES);
  k_hist<<<(N_EDGES + 255) / 256, 256, 0, stream>>>(dst, cur);
  k_scan<<<1, 256, 0, stream>>>(cur, off);
  k_scatter<<<(N_EDGES + 255) / 256, 256, 0, stream>>>(dst, cur, eids);
  k_sortgather<<<(N_NODES + 3) / 4, 256, 0, stream>>>(off, eids, src, (const float4*)eattr,
                                                      src_s, eattr_s);

  // node encoder -> hc and u (layer-0 input)
  k_enc<<<(N_NODES * 64 + 255) / 256, 256, 0, stream>>>(x, W_node, b_node, hcb, u);

  for (int l = 0; l < LAYERS; l++) {
    k_edge_agg<<<(N_NODES + 3) / 4, 256, 0, stream>>>(u, eattr_s, src_s, W_edge, b_edge,
                                                      off, t, l, htmp);
    int nxt = (l + 1 < LAYERS) ? (l + 1) : 0;  // unused when writeU=0
    k_mlp<<<NT_TILES, 256, 0, stream>>>(htmp, hcb, u,
                                        W1 + (size_t)l * DIM * HID, b1 + (size_t)l * HID,
                                        g1 + (size_t)l * HID, be1 + (size_t)l * HID,
                                        W2 + (size_t)l * HID * DIM, b2 + (size_t)l * DIM,
                                        ln_g + (size_t)nxt * DIM, ln_b + (size_t)nxt * DIM,
                                        (l > 0) ? 1 : 0, (l < LAYERS - 1) ? 1 : 0);
  }

  k_final<<<(N_NODES + 3) / 4, 256, 0, stream>>>(hcb, ln_g, ln_b, W_out, b_out, out);
}